// Round 1
// baseline (3404.288 us; speedup 1.0000x reference)
//
#include <hip/hip_runtime.h>

#define D_IN 256
#define D_HID 512
#define D_OUT 256
#define LN_EPS 1e-5f

// ---------------------------------------------------------------------------
// agg[n][d] = eps * v[n][d]   (epsilon residual folded into the init)
// ---------------------------------------------------------------------------
__global__ void init_agg_kernel(const float* __restrict__ v,
                                const float* __restrict__ eps_p,
                                float* __restrict__ agg, int n4) {
    int i = blockIdx.x * 256 + threadIdx.x;
    if (i >= n4) return;
    float eps = eps_p[0];
    float4 val = ((const float4*)v)[i];
    float4 o;
    o.x = val.x * eps; o.y = val.y * eps; o.z = val.z * eps; o.w = val.w * eps;
    ((float4*)agg)[i] = o;
}

// ---------------------------------------------------------------------------
// agg[dst[e]] += edge_weight[e] * v[src[e]]   one wave (64 lanes) per edge,
// each lane owns 4 consecutive floats (float4 load, 4 atomic adds).
// ---------------------------------------------------------------------------
__global__ void scatter_kernel(const float* __restrict__ v,
                               const float* __restrict__ ew,
                               const int* __restrict__ src,
                               const int* __restrict__ dst,
                               float* __restrict__ agg, int E) {
    int e = blockIdx.x * 4 + (threadIdx.x >> 6);
    if (e >= E) return;
    int lane = threadIdx.x & 63;
    int s = src[e];
    int d = dst[e];
    float w = ew[e];
    float4 val = ((const float4*)(v + (size_t)s * D_IN))[lane];
    float* ad = agg + (size_t)d * D_IN + lane * 4;
    atomicAdd(ad + 0, val.x * w);
    atomicAdd(ad + 1, val.y * w);
    atomicAdd(ad + 2, val.z * w);
    atomicAdd(ad + 3, val.w * w);
}

// ---------------------------------------------------------------------------
// C[m][n] = sum_k A[m][k] * B[n][k] + bias[n]     (A row-major MxK, B row-major NxK)
// 64x64 tile per 256-thread block, 4x4 micro-tile per thread, BK=16.
// N must be a multiple of 64, K a multiple of 16; M guarded.
// ---------------------------------------------------------------------------
#define BM 64
#define BN 64
#define BK 16

__global__ __launch_bounds__(256) void gemm_bt_kernel(
    const float* __restrict__ A, const float* __restrict__ B,
    const float* __restrict__ bias, float* __restrict__ C,
    int M, int N, int K) {
    __shared__ float As[BM][BK + 1];
    __shared__ float Bs[BN][BK + 1];

    int t = threadIdx.x;
    int tx = t & 15;        // 0..15 -> output col group
    int ty = t >> 4;        // 0..15 -> output row group
    int row0 = blockIdx.y * BM;
    int col0 = blockIdx.x * BN;

    int lrow = t >> 2;          // 0..63  (tile row to load)
    int lcol = (t & 3) * 4;     // 0,4,8,12 (k offset, float4)

    float acc[4][4] = {{0.f}};

    for (int k0 = 0; k0 < K; k0 += BK) {
        int ar = row0 + lrow;
        float4 av = (ar < M)
            ? ((const float4*)(A + (size_t)ar * K + k0 + lcol))[0]
            : make_float4(0.f, 0.f, 0.f, 0.f);
        As[lrow][lcol + 0] = av.x;
        As[lrow][lcol + 1] = av.y;
        As[lrow][lcol + 2] = av.z;
        As[lrow][lcol + 3] = av.w;

        int br = col0 + lrow;   // always < N (N multiple of 64)
        float4 bv = ((const float4*)(B + (size_t)br * K + k0 + lcol))[0];
        Bs[lrow][lcol + 0] = bv.x;
        Bs[lrow][lcol + 1] = bv.y;
        Bs[lrow][lcol + 2] = bv.z;
        Bs[lrow][lcol + 3] = bv.w;

        __syncthreads();

        #pragma unroll
        for (int kk = 0; kk < BK; ++kk) {
            float a[4], b[4];
            #pragma unroll
            for (int i = 0; i < 4; ++i) a[i] = As[ty * 4 + i][kk];
            #pragma unroll
            for (int j = 0; j < 4; ++j) b[j] = Bs[tx * 4 + j][kk];
            #pragma unroll
            for (int i = 0; i < 4; ++i)
                #pragma unroll
                for (int j = 0; j < 4; ++j)
                    acc[i][j] += a[i] * b[j];
        }
        __syncthreads();
    }

    #pragma unroll
    for (int i = 0; i < 4; ++i) {
        int r = row0 + ty * 4 + i;
        if (r >= M) continue;
        #pragma unroll
        for (int j = 0; j < 4; ++j) {
            int c = col0 + tx * 4 + j;
            C[(size_t)r * N + c] = acc[i][j] + bias[c];
        }
    }
}

// ---------------------------------------------------------------------------
// In-place LayerNorm(+affine) + ReLU over rows of length D (D multiple of 64).
// One 64-lane wave per row, 4 waves per block.
// ---------------------------------------------------------------------------
template <int D>
__global__ void ln_relu_kernel(float* __restrict__ x,
                               const float* __restrict__ g,
                               const float* __restrict__ beta, int nrows) {
    constexpr int PER = D / 64;
    int row = blockIdx.x * 4 + (threadIdx.x >> 6);
    if (row >= nrows) return;
    int lane = threadIdx.x & 63;
    float* xr = x + (size_t)row * D;

    float vals[PER];
    float sum = 0.f, sq = 0.f;
    #pragma unroll
    for (int i = 0; i < PER; ++i) {
        vals[i] = xr[lane + i * 64];
        sum += vals[i];
        sq += vals[i] * vals[i];
    }
    #pragma unroll
    for (int o = 32; o > 0; o >>= 1) {
        sum += __shfl_xor(sum, o, 64);
        sq  += __shfl_xor(sq, o, 64);
    }
    float mu = sum / (float)D;
    float var = sq / (float)D - mu * mu;
    float rstd = rsqrtf(var + LN_EPS);
    #pragma unroll
    for (int i = 0; i < PER; ++i) {
        int c = lane + i * 64;
        float y = (vals[i] - mu) * rstd * g[c] + beta[c];
        xr[c] = fmaxf(y, 0.f);
    }
}

// ---------------------------------------------------------------------------
extern "C" void kernel_launch(void* const* d_in, const int* in_sizes, int n_in,
                              void* d_out, int out_size, void* d_ws, size_t ws_size,
                              hipStream_t stream) {
    const float* v     = (const float*)d_in[0];
    const float* ew    = (const float*)d_in[1];
    const float* eps   = (const float*)d_in[2];
    const float* w1    = (const float*)d_in[3];
    const float* b1    = (const float*)d_in[4];
    const float* g1    = (const float*)d_in[5];
    const float* beta1 = (const float*)d_in[6];
    const float* w2    = (const float*)d_in[7];
    const float* b2    = (const float*)d_in[8];
    const float* g2    = (const float*)d_in[9];
    const float* beta2 = (const float*)d_in[10];
    const int*   src   = (const int*)d_in[11];
    const int*   dst   = (const int*)d_in[12];

    int N = in_sizes[0] / D_IN;     // 50000
    int E = in_sizes[1];            // 800000

    float* out = (float*)d_out;
    float* agg = (float*)d_ws;                       // [N, D_IN]
    float* h1  = agg + (size_t)N * D_IN;             // [N, D_HID]

    // 1) agg = eps * v
    int n4 = N * D_IN / 4;
    init_agg_kernel<<<(n4 + 255) / 256, 256, 0, stream>>>(v, eps, agg, n4);

    // 2) agg[dst] += w * v[src]
    scatter_kernel<<<(E + 3) / 4, 256, 0, stream>>>(v, ew, src, dst, agg, E);

    // 3) h1 = agg @ w1^T + b1
    dim3 grid1(D_HID / BN, (N + BM - 1) / BM);
    gemm_bt_kernel<<<grid1, 256, 0, stream>>>(agg, w1, b1, h1, N, D_HID, D_IN);

    // 4) h1 = relu(LN(h1))
    ln_relu_kernel<D_HID><<<(N + 3) / 4, 256, 0, stream>>>(h1, g1, beta1, N);

    // 5) out = h1 @ w2^T + b2
    dim3 grid2(D_OUT / BN, (N + BM - 1) / BM);
    gemm_bt_kernel<<<grid2, 256, 0, stream>>>(h1, w2, b2, out, N, D_OUT, D_HID);

    // 6) out = relu(LN(out))
    ln_relu_kernel<D_OUT><<<(N + 3) / 4, 256, 0, stream>>>(out, g2, beta2, N);
}

// Round 2
// 900.840 us; speedup vs baseline: 3.7790x; 3.7790x over previous
//
#include <hip/hip_runtime.h>

#define D_IN 256
#define D_HID 512
#define D_OUT 256
#define LN_EPS 1e-5f
#define SCAN_B 512

// ---------------------------------------------------------------------------
__global__ void zero_kernel(int* __restrict__ p, int n) {
    int i = blockIdx.x * 256 + threadIdx.x;
    if (i < n) p[i] = 0;
}

// cnt[dst[e]] += 1
__global__ void hist_kernel(const int* __restrict__ dst, int* __restrict__ cnt, int E) {
    int e = blockIdx.x * 256 + threadIdx.x;
    if (e < E) atomicAdd(&cnt[dst[e]], 1);
}

// per-block exclusive scan; block totals to bsum
__global__ __launch_bounds__(SCAN_B) void scan1_kernel(const int* __restrict__ cnt,
                                                       int* __restrict__ offs,
                                                       int* __restrict__ bsum, int n) {
    __shared__ int s[SCAN_B];
    int i = blockIdx.x * SCAN_B + threadIdx.x;
    int x = (i < n) ? cnt[i] : 0;
    s[threadIdx.x] = x;
    __syncthreads();
    for (int o = 1; o < SCAN_B; o <<= 1) {
        int t = (threadIdx.x >= (unsigned)o) ? s[threadIdx.x - o] : 0;
        __syncthreads();
        s[threadIdx.x] += t;
        __syncthreads();
    }
    if (i < n) offs[i] = s[threadIdx.x] - x;            // exclusive
    if (threadIdx.x == SCAN_B - 1) bsum[blockIdx.x] = s[threadIdx.x];
}

// scan the (<=128) block sums in one block
__global__ __launch_bounds__(128) void scan2_kernel(int* __restrict__ bsum, int nb) {
    __shared__ int s[128];
    int x = (threadIdx.x < (unsigned)nb) ? bsum[threadIdx.x] : 0;
    s[threadIdx.x] = x;
    __syncthreads();
    for (int o = 1; o < 128; o <<= 1) {
        int t = (threadIdx.x >= (unsigned)o) ? s[threadIdx.x - o] : 0;
        __syncthreads();
        s[threadIdx.x] += t;
        __syncthreads();
    }
    if (threadIdx.x < (unsigned)nb) bsum[threadIdx.x] = s[threadIdx.x] - x;  // exclusive
}

// offs[i] += bsum[block];  cursor = offs;  offs[n] = E
__global__ __launch_bounds__(SCAN_B) void scan3_kernel(int* __restrict__ offs,
                                                       int* __restrict__ cursor,
                                                       const int* __restrict__ bsum,
                                                       int n, int E) {
    int i = blockIdx.x * SCAN_B + threadIdx.x;
    if (i < n) {
        int v0 = offs[i] + bsum[blockIdx.x];
        offs[i] = v0;
        cursor[i] = v0;
    }
    if (i == 0) offs[n] = E;
}

// counting-sort fill: perm_src/perm_w grouped by dst
__global__ void fill_kernel(const int* __restrict__ src, const int* __restrict__ dst,
                            const float* __restrict__ ew, int* __restrict__ cursor,
                            int* __restrict__ perm_src, float* __restrict__ perm_w, int E) {
    int e = blockIdx.x * 256 + threadIdx.x;
    if (e >= E) return;
    int p = atomicAdd(&cursor[dst[e]], 1);
    perm_src[p] = src[e];
    perm_w[p] = ew[e];
}

// ---------------------------------------------------------------------------
// agg[n] = eps*v[n] + sum_{e: dst=n} w_e * v[src_e]    one wave per node
// ---------------------------------------------------------------------------
__global__ __launch_bounds__(256) void aggregate_kernel(
    const float* __restrict__ v, const float* __restrict__ eps_p,
    const int* __restrict__ offs, const int* __restrict__ perm_src,
    const float* __restrict__ perm_w, float* __restrict__ agg, int N) {
    int node = blockIdx.x * 4 + (threadIdx.x >> 6);
    if (node >= N) return;
    int lane = threadIdx.x & 63;
    int beg = offs[node], end = offs[node + 1];
    float4 acc = make_float4(0.f, 0.f, 0.f, 0.f);
    for (int i = beg; i < end; ++i) {
        int s = perm_src[i];       // wave-uniform -> scalar load
        float w = perm_w[i];
        float4 val = ((const float4*)(v + (size_t)s * D_IN))[lane];
        acc.x += w * val.x; acc.y += w * val.y;
        acc.z += w * val.z; acc.w += w * val.w;
    }
    float eps = eps_p[0];
    float4 mine = ((const float4*)(v + (size_t)node * D_IN))[lane];
    acc.x += eps * mine.x; acc.y += eps * mine.y;
    acc.z += eps * mine.z; acc.w += eps * mine.w;
    ((float4*)(agg + (size_t)node * D_IN))[lane] = acc;
}

// ---------------------------------------------------------------------------
// C[m][n] = sum_k A[m][k]*B[n][k] + bias[n]    64x64 tile, 4x4/thread, BK=16
// ---------------------------------------------------------------------------
#define BM 64
#define BN 64
#define BK 16

__global__ __launch_bounds__(256) void gemm_bt_kernel(
    const float* __restrict__ A, const float* __restrict__ B,
    const float* __restrict__ bias, float* __restrict__ C,
    int M, int N, int K) {
    __shared__ float As[BM][BK + 1];
    __shared__ float Bs[BN][BK + 1];

    int t = threadIdx.x;
    int tx = t & 15;
    int ty = t >> 4;
    int row0 = blockIdx.y * BM;
    int col0 = blockIdx.x * BN;

    int lrow = t >> 2;
    int lcol = (t & 3) * 4;

    float acc[4][4] = {{0.f}};

    for (int k0 = 0; k0 < K; k0 += BK) {
        int ar = row0 + lrow;
        float4 av = (ar < M)
            ? ((const float4*)(A + (size_t)ar * K + k0 + lcol))[0]
            : make_float4(0.f, 0.f, 0.f, 0.f);
        As[lrow][lcol + 0] = av.x;
        As[lrow][lcol + 1] = av.y;
        As[lrow][lcol + 2] = av.z;
        As[lrow][lcol + 3] = av.w;

        int br = col0 + lrow;
        float4 bv = ((const float4*)(B + (size_t)br * K + k0 + lcol))[0];
        Bs[lrow][lcol + 0] = bv.x;
        Bs[lrow][lcol + 1] = bv.y;
        Bs[lrow][lcol + 2] = bv.z;
        Bs[lrow][lcol + 3] = bv.w;

        __syncthreads();

        #pragma unroll
        for (int kk = 0; kk < BK; ++kk) {
            float a[4], b[4];
            #pragma unroll
            for (int i = 0; i < 4; ++i) a[i] = As[ty * 4 + i][kk];
            #pragma unroll
            for (int j = 0; j < 4; ++j) b[j] = Bs[tx * 4 + j][kk];
            #pragma unroll
            for (int i = 0; i < 4; ++i)
                #pragma unroll
                for (int j = 0; j < 4; ++j)
                    acc[i][j] += a[i] * b[j];
        }
        __syncthreads();
    }

    #pragma unroll
    for (int i = 0; i < 4; ++i) {
        int r = row0 + ty * 4 + i;
        if (r >= M) continue;
        #pragma unroll
        for (int j = 0; j < 4; ++j) {
            int c = col0 + tx * 4 + j;
            C[(size_t)r * N + c] = acc[i][j] + bias[c];
        }
    }
}

// ---------------------------------------------------------------------------
// In-place LayerNorm + ReLU, one wave per row
// ---------------------------------------------------------------------------
template <int D>
__global__ void ln_relu_kernel(float* __restrict__ x,
                               const float* __restrict__ g,
                               const float* __restrict__ beta, int nrows) {
    constexpr int PER = D / 64;
    int row = blockIdx.x * 4 + (threadIdx.x >> 6);
    if (row >= nrows) return;
    int lane = threadIdx.x & 63;
    float* xr = x + (size_t)row * D;

    float vals[PER];
    float sum = 0.f, sq = 0.f;
    #pragma unroll
    for (int i = 0; i < PER; ++i) {
        vals[i] = xr[lane + i * 64];
        sum += vals[i];
        sq += vals[i] * vals[i];
    }
    #pragma unroll
    for (int o = 32; o > 0; o >>= 1) {
        sum += __shfl_xor(sum, o, 64);
        sq  += __shfl_xor(sq, o, 64);
    }
    float mu = sum / (float)D;
    float var = sq / (float)D - mu * mu;
    float rstd = rsqrtf(var + LN_EPS);
    #pragma unroll
    for (int i = 0; i < PER; ++i) {
        int c = lane + i * 64;
        float y = (vals[i] - mu) * rstd * g[c] + beta[c];
        xr[c] = fmaxf(y, 0.f);
    }
}

// ---------------------------------------------------------------------------
extern "C" void kernel_launch(void* const* d_in, const int* in_sizes, int n_in,
                              void* d_out, int out_size, void* d_ws, size_t ws_size,
                              hipStream_t stream) {
    const float* v     = (const float*)d_in[0];
    const float* ew    = (const float*)d_in[1];
    const float* eps   = (const float*)d_in[2];
    const float* w1    = (const float*)d_in[3];
    const float* b1    = (const float*)d_in[4];
    const float* g1    = (const float*)d_in[5];
    const float* beta1 = (const float*)d_in[6];
    const float* w2    = (const float*)d_in[7];
    const float* b2    = (const float*)d_in[8];
    const float* g2    = (const float*)d_in[9];
    const float* beta2 = (const float*)d_in[10];
    const int*   src   = (const int*)d_in[11];
    const int*   dst   = (const int*)d_in[12];

    int N = in_sizes[0] / D_IN;     // 50000
    int E = in_sizes[1];            // 800000

    float* out = (float*)d_out;
    float* agg = (float*)d_ws;                       // [N, D_IN]
    float* h1  = agg + (size_t)N * D_IN;             // [N, D_HID]

    // CSR scratch overlaid in h1's region (dead before gemm1 writes h1)
    int*   offs     = (int*)h1;                      // N+1
    int*   cursor   = offs + (N + 1);                // N  (doubles as cnt)
    int*   bsum     = cursor + N;                    // 128
    int*   perm_src = bsum + 128;                    // E
    float* perm_w   = (float*)(perm_src + E);        // E

    int nb = (N + SCAN_B - 1) / SCAN_B;              // 98

    // 1) build CSR by dst
    zero_kernel<<<(N + 255) / 256, 256, 0, stream>>>(cursor, N);
    hist_kernel<<<(E + 255) / 256, 256, 0, stream>>>(dst, cursor, E);
    scan1_kernel<<<nb, SCAN_B, 0, stream>>>(cursor, offs, bsum, N);
    scan2_kernel<<<1, 128, 0, stream>>>(bsum, nb);
    scan3_kernel<<<nb, SCAN_B, 0, stream>>>(offs, cursor, bsum, N, E);
    fill_kernel<<<(E + 255) / 256, 256, 0, stream>>>(src, dst, ew, cursor, perm_src, perm_w, E);

    // 2) agg = eps*v + gather-sum
    aggregate_kernel<<<(N + 3) / 4, 256, 0, stream>>>(v, eps, offs, perm_src, perm_w, agg, N);

    // 3) h1 = agg @ w1^T + b1
    dim3 grid1(D_HID / BN, (N + BM - 1) / BM);
    gemm_bt_kernel<<<grid1, 256, 0, stream>>>(agg, w1, b1, h1, N, D_HID, D_IN);

    // 4) h1 = relu(LN(h1))
    ln_relu_kernel<D_HID><<<(N + 3) / 4, 256, 0, stream>>>(h1, g1, beta1, N);

    // 5) out = h1 @ w2^T + b2
    dim3 grid2(D_OUT / BN, (N + BM - 1) / BM);
    gemm_bt_kernel<<<grid2, 256, 0, stream>>>(h1, w2, b2, out, N, D_OUT, D_HID);

    // 6) out = relu(LN(out))
    ln_relu_kernel<D_OUT><<<(N + 3) / 4, 256, 0, stream>>>(out, g2, beta2, N);
}

// Round 4
// 440.358 us; speedup vs baseline: 7.7307x; 2.0457x over previous
//
#include <hip/hip_runtime.h>

#define D_IN 256
#define D_HID 512
#define D_OUT 256
#define LN_EPS 1e-5f
#define SCAN_B 512

typedef __attribute__((ext_vector_type(8))) short bf16x8;
typedef __attribute__((ext_vector_type(4))) float f32x4;

__device__ __forceinline__ ushort f2bf(float x) {
    union { float f; unsigned u; } c; c.f = x;
    unsigned r = c.u + 0x7FFFu + ((c.u >> 16) & 1u);   // round-to-nearest-even
    return (ushort)(r >> 16);
}
__device__ __forceinline__ float bf2f(unsigned b) {
    union { unsigned u; float f; } c; c.u = b << 16;
    return c.f;
}

// ---------------------------------------------------------------------------
// CSR build (counting sort by dst)
// ---------------------------------------------------------------------------
__global__ void zero_kernel(int* __restrict__ p, int n) {
    int i = blockIdx.x * 256 + threadIdx.x;
    if (i < n) p[i] = 0;
}

__global__ void hist_kernel(const int* __restrict__ dst, int* __restrict__ cnt, int E) {
    int e = blockIdx.x * 256 + threadIdx.x;
    if (e < E) atomicAdd(&cnt[dst[e]], 1);
}

__global__ __launch_bounds__(SCAN_B) void scan1_kernel(const int* __restrict__ cnt,
                                                       int* __restrict__ offs,
                                                       int* __restrict__ bsum, int n) {
    __shared__ int s[SCAN_B];
    int i = blockIdx.x * SCAN_B + threadIdx.x;
    int x = (i < n) ? cnt[i] : 0;
    s[threadIdx.x] = x;
    __syncthreads();
    for (int o = 1; o < SCAN_B; o <<= 1) {
        int t = (threadIdx.x >= (unsigned)o) ? s[threadIdx.x - o] : 0;
        __syncthreads();
        s[threadIdx.x] += t;
        __syncthreads();
    }
    if (i < n) offs[i] = s[threadIdx.x] - x;
    if (threadIdx.x == SCAN_B - 1) bsum[blockIdx.x] = s[threadIdx.x];
}

__global__ __launch_bounds__(128) void scan2_kernel(int* __restrict__ bsum, int nb) {
    __shared__ int s[128];
    int x = (threadIdx.x < (unsigned)nb) ? bsum[threadIdx.x] : 0;
    s[threadIdx.x] = x;
    __syncthreads();
    for (int o = 1; o < 128; o <<= 1) {
        int t = (threadIdx.x >= (unsigned)o) ? s[threadIdx.x - o] : 0;
        __syncthreads();
        s[threadIdx.x] += t;
        __syncthreads();
    }
    if (threadIdx.x < (unsigned)nb) bsum[threadIdx.x] = s[threadIdx.x] - x;
}

__global__ __launch_bounds__(SCAN_B) void scan3_kernel(int* __restrict__ offs,
                                                       int* __restrict__ cursor,
                                                       const int* __restrict__ bsum,
                                                       int n, int E) {
    int i = blockIdx.x * SCAN_B + threadIdx.x;
    if (i < n) {
        int v0 = offs[i] + bsum[blockIdx.x];
        offs[i] = v0;
        cursor[i] = v0;
    }
    if (i == 0) offs[n] = E;
}

__global__ void fill_kernel(const int* __restrict__ src, const int* __restrict__ dst,
                            const float* __restrict__ ew, int* __restrict__ cursor,
                            int* __restrict__ perm_src, float* __restrict__ perm_w, int E) {
    int e = blockIdx.x * 256 + threadIdx.x;
    if (e >= E) return;
    int p = atomicAdd(&cursor[dst[e]], 1);
    perm_src[p] = src[e];
    perm_w[p] = ew[e];
}

// ---------------------------------------------------------------------------
// agg_bf16[n] = bf16( eps*v[n] + sum_{e:dst=n} w_e * v[src_e] )  one wave/node
// ---------------------------------------------------------------------------
__global__ __launch_bounds__(256) void aggregate_kernel(
    const float* __restrict__ v, const float* __restrict__ eps_p,
    const int* __restrict__ offs, const int* __restrict__ perm_src,
    const float* __restrict__ perm_w, ushort* __restrict__ aggb, int N) {
    int node = blockIdx.x * 4 + (threadIdx.x >> 6);
    if (node >= N) return;
    int lane = threadIdx.x & 63;
    int beg = offs[node], end = offs[node + 1];
    float4 acc = make_float4(0.f, 0.f, 0.f, 0.f);
    for (int i = beg; i < end; ++i) {
        int s = perm_src[i];
        float w = perm_w[i];
        float4 val = ((const float4*)(v + (size_t)s * D_IN))[lane];
        acc.x += w * val.x; acc.y += w * val.y;
        acc.z += w * val.z; acc.w += w * val.w;
    }
    float eps = eps_p[0];
    float4 mine = ((const float4*)(v + (size_t)node * D_IN))[lane];
    acc.x += eps * mine.x; acc.y += eps * mine.y;
    acc.z += eps * mine.z; acc.w += eps * mine.w;
    ushort4 o = make_ushort4(f2bf(acc.x), f2bf(acc.y), f2bf(acc.z), f2bf(acc.w));
    ((ushort4*)(aggb + (size_t)node * D_IN))[lane] = o;
}

// ---------------------------------------------------------------------------
// fp32 -> bf16 conversion (weights)
// ---------------------------------------------------------------------------
__global__ void cvt_bf16_kernel(const float* __restrict__ in, ushort* __restrict__ out, int n4) {
    int i = blockIdx.x * 256 + threadIdx.x;
    if (i >= n4) return;
    float4 x = ((const float4*)in)[i];
    ((ushort4*)out)[i] = make_ushort4(f2bf(x.x), f2bf(x.y), f2bf(x.z), f2bf(x.w));
}

// ---------------------------------------------------------------------------
// bf16 MFMA GEMM: C[m][n] = sum_k A[m][k]*B[n][k] + bias[n]
// 128x128 tile, 4 waves (2x2), 4x4 16x16x32 fragments/wave, BK=32,
// global_load_lds width-16 staging. N,K multiples of 128/32; M guarded.
// ---------------------------------------------------------------------------
template <int WRITE_BF16>
__global__ __launch_bounds__(256) void gemm_mfma_kernel(
    const ushort* __restrict__ A, const ushort* __restrict__ B,
    const float* __restrict__ bias, void* __restrict__ Cv,
    int M, int N, int K) {
    __shared__ ushort As[128 * 32];
    __shared__ ushort Bs[128 * 32];

    int t = threadIdx.x;
    int w = t >> 6;
    int lane = t & 63;
    int row0 = blockIdx.y * 128;
    int col0 = blockIdx.x * 128;
    int wm = w >> 1, wn = w & 1;

    int srow = t >> 2;          // 0..63 staging row within 64-row half
    int scol = (t & 3) * 8;     // k-offset in elements (8 bf16 = 16B)

    f32x4 acc[4][4];
    #pragma unroll
    for (int i = 0; i < 4; ++i)
        #pragma unroll
        for (int j = 0; j < 4; ++j) {
            f32x4 z = {0.f, 0.f, 0.f, 0.f};
            acc[i][j] = z;
        }

    int fr = lane & 15;          // fragment row (m or n)
    int kb = (lane >> 4) * 8;    // fragment k base
    int quad = lane >> 4;

    for (int k0 = 0; k0 < K; k0 += 32) {
        #pragma unroll
        for (int j = 0; j < 2; ++j) {
            int ar = row0 + j * 64 + srow;
            if (ar > M - 1) ar = M - 1;
            const ushort* gpa = A + (size_t)ar * K + k0 + scol;
            __builtin_amdgcn_global_load_lds(
                (const __attribute__((address_space(1))) void*)gpa,
                (__attribute__((address_space(3))) void*)(&As[j * 2048 + w * 512]),
                16, 0, 0);
            int br = col0 + j * 64 + srow;
            const ushort* gpb = B + (size_t)br * K + k0 + scol;
            __builtin_amdgcn_global_load_lds(
                (const __attribute__((address_space(1))) void*)gpb,
                (__attribute__((address_space(3))) void*)(&Bs[j * 2048 + w * 512]),
                16, 0, 0);
        }
        __syncthreads();

        bf16x8 af[4], bfr[4];
        #pragma unroll
        for (int i = 0; i < 4; ++i)
            af[i] = *(const bf16x8*)&As[(wm * 64 + i * 16 + fr) * 32 + kb];
        #pragma unroll
        for (int j = 0; j < 4; ++j)
            bfr[j] = *(const bf16x8*)&Bs[(wn * 64 + j * 16 + fr) * 32 + kb];
        #pragma unroll
        for (int i = 0; i < 4; ++i)
            #pragma unroll
            for (int j = 0; j < 4; ++j)
                acc[i][j] = __builtin_amdgcn_mfma_f32_16x16x32_bf16(af[i], bfr[j], acc[i][j], 0, 0, 0);
        __syncthreads();
    }

    // C/D layout: col = lane&15, row = quad*4 + reg
    #pragma unroll
    for (int i = 0; i < 4; ++i) {
        #pragma unroll
        for (int r = 0; r < 4; ++r) {
            int row = row0 + wm * 64 + i * 16 + quad * 4 + r;
            if (row >= M) continue;
            #pragma unroll
            for (int j = 0; j < 4; ++j) {
                int col = col0 + wn * 64 + j * 16 + fr;
                float val = acc[i][j][r] + bias[col];
                if (WRITE_BF16)
                    ((ushort*)Cv)[(size_t)row * N + col] = f2bf(val);
                else
                    ((float*)Cv)[(size_t)row * N + col] = val;
            }
        }
    }
}

// ---------------------------------------------------------------------------
// LayerNorm + ReLU on bf16 rows of length 512 (in-place), one wave per row
// ---------------------------------------------------------------------------
__global__ void ln_relu_bf16_kernel(ushort* __restrict__ x,
                                    const float* __restrict__ g,
                                    const float* __restrict__ beta, int nrows) {
    int row = blockIdx.x * 4 + (threadIdx.x >> 6);
    if (row >= nrows) return;
    int lane = threadIdx.x & 63;
    ushort* xr = x + (size_t)row * D_HID;

    uint4 q = ((const uint4*)xr)[lane];
    float v[8];
    v[0] = bf2f(q.x & 0xffffu); v[1] = bf2f(q.x >> 16);
    v[2] = bf2f(q.y & 0xffffu); v[3] = bf2f(q.y >> 16);
    v[4] = bf2f(q.z & 0xffffu); v[5] = bf2f(q.z >> 16);
    v[6] = bf2f(q.w & 0xffffu); v[7] = bf2f(q.w >> 16);

    float sum = 0.f, sq = 0.f;
    #pragma unroll
    for (int j = 0; j < 8; ++j) { sum += v[j]; sq += v[j] * v[j]; }
    #pragma unroll
    for (int o = 32; o > 0; o >>= 1) {
        sum += __shfl_xor(sum, o, 64);
        sq  += __shfl_xor(sq, o, 64);
    }
    float mu = sum / (float)D_HID;
    float var = sq / (float)D_HID - mu * mu;
    float rstd = rsqrtf(var + LN_EPS);

    int c0 = lane * 8;
    float4 ga = ((const float4*)(g + c0))[0];
    float4 gb = ((const float4*)(g + c0))[1];
    float4 ba = ((const float4*)(beta + c0))[0];
    float4 bb = ((const float4*)(beta + c0))[1];
    float gg[8] = {ga.x, ga.y, ga.z, ga.w, gb.x, gb.y, gb.z, gb.w};
    float bt[8] = {ba.x, ba.y, ba.z, ba.w, bb.x, bb.y, bb.z, bb.w};

    unsigned p[8];
    #pragma unroll
    for (int j = 0; j < 8; ++j) {
        float y = (v[j] - mu) * rstd * gg[j] + bt[j];
        p[j] = f2bf(fmaxf(y, 0.f));
    }
    q.x = p[0] | (p[1] << 16);
    q.y = p[2] | (p[3] << 16);
    q.z = p[4] | (p[5] << 16);
    q.w = p[6] | (p[7] << 16);
    ((uint4*)xr)[lane] = q;
}

// ---------------------------------------------------------------------------
// LayerNorm + ReLU on fp32 rows (in-place), one wave per row
// ---------------------------------------------------------------------------
template <int D>
__global__ void ln_relu_kernel(float* __restrict__ x,
                               const float* __restrict__ g,
                               const float* __restrict__ beta, int nrows) {
    constexpr int PER = D / 64;
    int row = blockIdx.x * 4 + (threadIdx.x >> 6);
    if (row >= nrows) return;
    int lane = threadIdx.x & 63;
    float* xr = x + (size_t)row * D;

    float vals[PER];
    float sum = 0.f, sq = 0.f;
    #pragma unroll
    for (int i = 0; i < PER; ++i) {
        vals[i] = xr[lane + i * 64];
        sum += vals[i];
        sq += vals[i] * vals[i];
    }
    #pragma unroll
    for (int o = 32; o > 0; o >>= 1) {
        sum += __shfl_xor(sum, o, 64);
        sq  += __shfl_xor(sq, o, 64);
    }
    float mu = sum / (float)D;
    float var = sq / (float)D - mu * mu;
    float rstd = rsqrtf(var + LN_EPS);
    #pragma unroll
    for (int i = 0; i < PER; ++i) {
        int c = lane + i * 64;
        float y = (vals[i] - mu) * rstd * g[c] + beta[c];
        xr[c] = fmaxf(y, 0.f);
    }
}

// ---------------------------------------------------------------------------
extern "C" void kernel_launch(void* const* d_in, const int* in_sizes, int n_in,
                              void* d_out, int out_size, void* d_ws, size_t ws_size,
                              hipStream_t stream) {
    const float* v     = (const float*)d_in[0];
    const float* ew    = (const float*)d_in[1];
    const float* eps   = (const float*)d_in[2];
    const float* w1    = (const float*)d_in[3];
    const float* b1    = (const float*)d_in[4];
    const float* g1    = (const float*)d_in[5];
    const float* beta1 = (const float*)d_in[6];
    const float* w2    = (const float*)d_in[7];
    const float* b2    = (const float*)d_in[8];
    const float* g2    = (const float*)d_in[9];
    const float* beta2 = (const float*)d_in[10];
    const int*   src   = (const int*)d_in[11];
    const int*   dst   = (const int*)d_in[12];

    int N = in_sizes[0] / D_IN;     // 50000
    int E = in_sizes[1];            // 800000

    float* out = (float*)d_out;

    // workspace layout (256B-aligned chunks)
    char* ws = (char*)d_ws;
    size_t off = 0;
    ushort* aggb = (ushort*)(ws + off); off += (size_t)N * D_IN * 2;            // 25.6 MB
    ushort* h1b  = (ushort*)(ws + off); off += (size_t)N * D_HID * 2;           // 51.2 MB
    ushort* w1b  = (ushort*)(ws + off); off += (size_t)D_HID * D_IN * 2;        // 256 KB
    ushort* w2b  = (ushort*)(ws + off); off += (size_t)D_OUT * D_HID * 2;       // 256 KB
    int* offs     = (int*)(ws + off); off += (size_t)(N + 256) * 4;
    int* cursor   = (int*)(ws + off); off += (size_t)(N + 256) * 4;
    int* bsum     = (int*)(ws + off); off += 1024;
    int* perm_src = (int*)(ws + off); off += (size_t)E * 4;
    float* perm_w = (float*)(ws + off); off += (size_t)E * 4;

    int nb = (N + SCAN_B - 1) / SCAN_B;

    // 1) CSR by dst
    zero_kernel<<<(N + 255) / 256, 256, 0, stream>>>(cursor, N);
    hist_kernel<<<(E + 255) / 256, 256, 0, stream>>>(dst, cursor, E);
    scan1_kernel<<<nb, SCAN_B, 0, stream>>>(cursor, offs, bsum, N);
    scan2_kernel<<<1, 128, 0, stream>>>(bsum, nb);
    scan3_kernel<<<nb, SCAN_B, 0, stream>>>(offs, cursor, bsum, N, E);
    fill_kernel<<<(E + 255) / 256, 256, 0, stream>>>(src, dst, ew, cursor, perm_src, perm_w, E);

    // 2) aggregate -> bf16
    aggregate_kernel<<<(N + 3) / 4, 256, 0, stream>>>(v, eps, offs, perm_src, perm_w, aggb, N);

    // 3) weights -> bf16
    cvt_bf16_kernel<<<(D_HID * D_IN / 4 + 255) / 256, 256, 0, stream>>>(w1, w1b, D_HID * D_IN / 4);
    cvt_bf16_kernel<<<(D_OUT * D_HID / 4 + 255) / 256, 256, 0, stream>>>(w2, w2b, D_OUT * D_HID / 4);

    // 4) h1b = bf16(aggb @ w1b^T + b1)
    dim3 grid1(D_HID / 128, (N + 127) / 128);
    gemm_mfma_kernel<1><<<grid1, 256, 0, stream>>>(aggb, w1b, b1, h1b, N, D_HID, D_IN);

    // 5) h1b = relu(LN(h1b)) in-place
    ln_relu_bf16_kernel<<<(N + 3) / 4, 256, 0, stream>>>(h1b, g1, beta1, N);

    // 6) out = h1b @ w2b^T + b2  (fp32)
    dim3 grid2(D_OUT / 128, (N + 127) / 128);
    gemm_mfma_kernel<0><<<grid2, 256, 0, stream>>>(h1b, w2b, b2, out, N, D_OUT, D_HID);

    // 7) out = relu(LN(out)) in-place
    ln_relu_kernel<D_OUT><<<(N + 3) / 4, 256, 0, stream>>>(out, g2, beta2, N);
}

// Round 5
// 387.566 us; speedup vs baseline: 8.7838x; 1.1362x over previous
//
#include <hip/hip_runtime.h>

#define D_IN 256
#define D_HID 512
#define D_OUT 256
#define LN_EPS 1e-5f
#define SCAN_B 512

typedef __attribute__((ext_vector_type(8))) short bf16x8;
typedef __attribute__((ext_vector_type(4))) float f32x4;

__device__ __forceinline__ ushort f2bf(float x) {
    union { float f; unsigned u; } c; c.f = x;
    unsigned r = c.u + 0x7FFFu + ((c.u >> 16) & 1u);   // round-to-nearest-even
    return (ushort)(r >> 16);
}
__device__ __forceinline__ float bf2f(unsigned b) {
    union { unsigned u; float f; } c; c.u = b << 16;
    return c.f;
}

// ---------------------------------------------------------------------------
// CSR build (counting sort by dst)
// ---------------------------------------------------------------------------
__global__ void zero_kernel(int* __restrict__ p, int n) {
    int i = blockIdx.x * 256 + threadIdx.x;
    if (i < n) p[i] = 0;
}

__global__ void hist_kernel(const int* __restrict__ dst, int* __restrict__ cnt, int E) {
    int e = blockIdx.x * 256 + threadIdx.x;
    if (e < E) atomicAdd(&cnt[dst[e]], 1);
}

__global__ __launch_bounds__(SCAN_B) void scan1_kernel(const int* __restrict__ cnt,
                                                       int* __restrict__ offs,
                                                       int* __restrict__ bsum, int n) {
    __shared__ int s[SCAN_B];
    int i = blockIdx.x * SCAN_B + threadIdx.x;
    int x = (i < n) ? cnt[i] : 0;
    s[threadIdx.x] = x;
    __syncthreads();
    for (int o = 1; o < SCAN_B; o <<= 1) {
        int t = (threadIdx.x >= (unsigned)o) ? s[threadIdx.x - o] : 0;
        __syncthreads();
        s[threadIdx.x] += t;
        __syncthreads();
    }
    if (i < n) offs[i] = s[threadIdx.x] - x;
    if (threadIdx.x == SCAN_B - 1) bsum[blockIdx.x] = s[threadIdx.x];
}

__global__ __launch_bounds__(128) void scan2_kernel(int* __restrict__ bsum, int nb) {
    __shared__ int s[128];
    int x = (threadIdx.x < (unsigned)nb) ? bsum[threadIdx.x] : 0;
    s[threadIdx.x] = x;
    __syncthreads();
    for (int o = 1; o < 128; o <<= 1) {
        int t = (threadIdx.x >= (unsigned)o) ? s[threadIdx.x - o] : 0;
        __syncthreads();
        s[threadIdx.x] += t;
        __syncthreads();
    }
    if (threadIdx.x < (unsigned)nb) bsum[threadIdx.x] = s[threadIdx.x] - x;
}

__global__ __launch_bounds__(SCAN_B) void scan3_kernel(int* __restrict__ offs,
                                                       int* __restrict__ cursor,
                                                       const int* __restrict__ bsum,
                                                       int n, int E) {
    int i = blockIdx.x * SCAN_B + threadIdx.x;
    if (i < n) {
        int v0 = offs[i] + bsum[blockIdx.x];
        offs[i] = v0;
        cursor[i] = v0;
    }
    if (i == 0) offs[n] = E;
}

__global__ void fill_kernel(const int* __restrict__ src, const int* __restrict__ dst,
                            const float* __restrict__ ew, int* __restrict__ cursor,
                            int* __restrict__ perm_src, float* __restrict__ perm_w, int E) {
    int e = blockIdx.x * 256 + threadIdx.x;
    if (e >= E) return;
    int p = atomicAdd(&cursor[dst[e]], 1);
    perm_src[p] = src[e];
    perm_w[p] = ew[e];
}

// ---------------------------------------------------------------------------
// fp32 -> bf16 conversion
// ---------------------------------------------------------------------------
__global__ void cvt_bf16_kernel(const float* __restrict__ in, ushort* __restrict__ out, int n4) {
    int i = blockIdx.x * 256 + threadIdx.x;
    if (i >= n4) return;
    float4 x = ((const float4*)in)[i];
    ((ushort4*)out)[i] = make_ushort4(f2bf(x.x), f2bf(x.y), f2bf(x.z), f2bf(x.w));
}

// ---------------------------------------------------------------------------
// agg_bf16[n] = bf16( eps*vb[n] + sum_{e:dst=n} w_e * vb[src_e] )
// one wave/node, bf16 gather (512 B/edge), edge loop unrolled x4 so 4
// independent row loads are in flight per iteration.
// ---------------------------------------------------------------------------
__global__ __launch_bounds__(256) void aggregate_kernel(
    const ushort* __restrict__ vb, const float* __restrict__ eps_p,
    const int* __restrict__ offs, const int* __restrict__ perm_src,
    const float* __restrict__ perm_w, ushort* __restrict__ aggb, int N) {
    int node = blockIdx.x * 4 + (threadIdx.x >> 6);
    if (node >= N) return;
    int lane = threadIdx.x & 63;
    int beg = offs[node], end = offs[node + 1];
    float a0 = 0.f, a1 = 0.f, a2 = 0.f, a3 = 0.f;

    int i = beg;
    for (; i + 4 <= end; i += 4) {
        int s0 = perm_src[i + 0], s1 = perm_src[i + 1];
        int s2 = perm_src[i + 2], s3 = perm_src[i + 3];
        float w0 = perm_w[i + 0], w1 = perm_w[i + 1];
        float w2 = perm_w[i + 2], w3 = perm_w[i + 3];
        ushort4 r0 = ((const ushort4*)(vb + (size_t)s0 * D_IN))[lane];
        ushort4 r1 = ((const ushort4*)(vb + (size_t)s1 * D_IN))[lane];
        ushort4 r2 = ((const ushort4*)(vb + (size_t)s2 * D_IN))[lane];
        ushort4 r3 = ((const ushort4*)(vb + (size_t)s3 * D_IN))[lane];
        a0 += w0 * bf2f(r0.x) + w1 * bf2f(r1.x) + w2 * bf2f(r2.x) + w3 * bf2f(r3.x);
        a1 += w0 * bf2f(r0.y) + w1 * bf2f(r1.y) + w2 * bf2f(r2.y) + w3 * bf2f(r3.y);
        a2 += w0 * bf2f(r0.z) + w1 * bf2f(r1.z) + w2 * bf2f(r2.z) + w3 * bf2f(r3.z);
        a3 += w0 * bf2f(r0.w) + w1 * bf2f(r1.w) + w2 * bf2f(r2.w) + w3 * bf2f(r3.w);
    }
    for (; i < end; ++i) {
        int s = perm_src[i];
        float w = perm_w[i];
        ushort4 r = ((const ushort4*)(vb + (size_t)s * D_IN))[lane];
        a0 += w * bf2f(r.x); a1 += w * bf2f(r.y);
        a2 += w * bf2f(r.z); a3 += w * bf2f(r.w);
    }
    float eps = eps_p[0];
    ushort4 m = ((const ushort4*)(vb + (size_t)node * D_IN))[lane];
    a0 += eps * bf2f(m.x); a1 += eps * bf2f(m.y);
    a2 += eps * bf2f(m.z); a3 += eps * bf2f(m.w);
    ((ushort4*)(aggb + (size_t)node * D_IN))[lane] =
        make_ushort4(f2bf(a0), f2bf(a1), f2bf(a2), f2bf(a3));
}

// ---------------------------------------------------------------------------
// bf16 MFMA GEMM: C[m][n] = sum_k A[m][k]*B[n][k] + bias[n]
// 128x128 tile, 4 waves (2x2), 4x4 16x16x32 fragments/wave, BK=32,
// global_load_lds width-16 staging. N,K multiples of 128/32; M guarded.
// ---------------------------------------------------------------------------
template <int WRITE_BF16>
__global__ __launch_bounds__(256) void gemm_mfma_kernel(
    const ushort* __restrict__ A, const ushort* __restrict__ B,
    const float* __restrict__ bias, void* __restrict__ Cv,
    int M, int N, int K) {
    __shared__ ushort As[128 * 32];
    __shared__ ushort Bs[128 * 32];

    int t = threadIdx.x;
    int w = t >> 6;
    int lane = t & 63;
    int row0 = blockIdx.y * 128;
    int col0 = blockIdx.x * 128;
    int wm = w >> 1, wn = w & 1;

    int srow = t >> 2;          // 0..63 staging row within 64-row half
    int scol = (t & 3) * 8;     // k-offset in elements (8 bf16 = 16B)

    f32x4 acc[4][4];
    #pragma unroll
    for (int i = 0; i < 4; ++i)
        #pragma unroll
        for (int j = 0; j < 4; ++j) {
            f32x4 z = {0.f, 0.f, 0.f, 0.f};
            acc[i][j] = z;
        }

    int fr = lane & 15;          // fragment row (m or n)
    int kb = (lane >> 4) * 8;    // fragment k base
    int quad = lane >> 4;

    for (int k0 = 0; k0 < K; k0 += 32) {
        #pragma unroll
        for (int j = 0; j < 2; ++j) {
            int ar = row0 + j * 64 + srow;
            if (ar > M - 1) ar = M - 1;
            const ushort* gpa = A + (size_t)ar * K + k0 + scol;
            __builtin_amdgcn_global_load_lds(
                (const __attribute__((address_space(1))) void*)gpa,
                (__attribute__((address_space(3))) void*)(&As[j * 2048 + w * 512]),
                16, 0, 0);
            int br = col0 + j * 64 + srow;
            const ushort* gpb = B + (size_t)br * K + k0 + scol;
            __builtin_amdgcn_global_load_lds(
                (const __attribute__((address_space(1))) void*)gpb,
                (__attribute__((address_space(3))) void*)(&Bs[j * 2048 + w * 512]),
                16, 0, 0);
        }
        __syncthreads();

        bf16x8 af[4], bfr[4];
        #pragma unroll
        for (int i = 0; i < 4; ++i)
            af[i] = *(const bf16x8*)&As[(wm * 64 + i * 16 + fr) * 32 + kb];
        #pragma unroll
        for (int j = 0; j < 4; ++j)
            bfr[j] = *(const bf16x8*)&Bs[(wn * 64 + j * 16 + fr) * 32 + kb];
        #pragma unroll
        for (int i = 0; i < 4; ++i)
            #pragma unroll
            for (int j = 0; j < 4; ++j)
                acc[i][j] = __builtin_amdgcn_mfma_f32_16x16x32_bf16(af[i], bfr[j], acc[i][j], 0, 0, 0);
        __syncthreads();
    }

    // C/D layout: col = lane&15, row = quad*4 + reg
    #pragma unroll
    for (int i = 0; i < 4; ++i) {
        #pragma unroll
        for (int r = 0; r < 4; ++r) {
            int row = row0 + wm * 64 + i * 16 + quad * 4 + r;
            if (row >= M) continue;
            #pragma unroll
            for (int j = 0; j < 4; ++j) {
                int col = col0 + wn * 64 + j * 16 + fr;
                float val = acc[i][j][r] + bias[col];
                if (WRITE_BF16)
                    ((ushort*)Cv)[(size_t)row * N + col] = f2bf(val);
                else
                    ((float*)Cv)[(size_t)row * N + col] = val;
            }
        }
    }
}

// ---------------------------------------------------------------------------
// LayerNorm + ReLU on bf16 rows of length 512 (in-place), one wave per row
// ---------------------------------------------------------------------------
__global__ void ln_relu_bf16_kernel(ushort* __restrict__ x,
                                    const float* __restrict__ g,
                                    const float* __restrict__ beta, int nrows) {
    int row = blockIdx.x * 4 + (threadIdx.x >> 6);
    if (row >= nrows) return;
    int lane = threadIdx.x & 63;
    ushort* xr = x + (size_t)row * D_HID;

    uint4 q = ((const uint4*)xr)[lane];
    float v[8];
    v[0] = bf2f(q.x & 0xffffu); v[1] = bf2f(q.x >> 16);
    v[2] = bf2f(q.y & 0xffffu); v[3] = bf2f(q.y >> 16);
    v[4] = bf2f(q.z & 0xffffu); v[5] = bf2f(q.z >> 16);
    v[6] = bf2f(q.w & 0xffffu); v[7] = bf2f(q.w >> 16);

    float sum = 0.f, sq = 0.f;
    #pragma unroll
    for (int j = 0; j < 8; ++j) { sum += v[j]; sq += v[j] * v[j]; }
    #pragma unroll
    for (int o = 32; o > 0; o >>= 1) {
        sum += __shfl_xor(sum, o, 64);
        sq  += __shfl_xor(sq, o, 64);
    }
    float mu = sum / (float)D_HID;
    float var = sq / (float)D_HID - mu * mu;
    float rstd = rsqrtf(var + LN_EPS);

    int c0 = lane * 8;
    float4 ga = ((const float4*)(g + c0))[0];
    float4 gb = ((const float4*)(g + c0))[1];
    float4 ba = ((const float4*)(beta + c0))[0];
    float4 bb = ((const float4*)(beta + c0))[1];
    float gg[8] = {ga.x, ga.y, ga.z, ga.w, gb.x, gb.y, gb.z, gb.w};
    float bt[8] = {ba.x, ba.y, ba.z, ba.w, bb.x, bb.y, bb.z, bb.w};

    unsigned p[8];
    #pragma unroll
    for (int j = 0; j < 8; ++j) {
        float y = (v[j] - mu) * rstd * gg[j] + bt[j];
        p[j] = f2bf(fmaxf(y, 0.f));
    }
    q.x = p[0] | (p[1] << 16);
    q.y = p[2] | (p[3] << 16);
    q.z = p[4] | (p[5] << 16);
    q.w = p[6] | (p[7] << 16);
    ((uint4*)xr)[lane] = q;
}

// ---------------------------------------------------------------------------
// LayerNorm + ReLU on fp32 rows (in-place), one wave per row
// ---------------------------------------------------------------------------
template <int D>
__global__ void ln_relu_kernel(float* __restrict__ x,
                               const float* __restrict__ g,
                               const float* __restrict__ beta, int nrows) {
    constexpr int PER = D / 64;
    int row = blockIdx.x * 4 + (threadIdx.x >> 6);
    if (row >= nrows) return;
    int lane = threadIdx.x & 63;
    float* xr = x + (size_t)row * D;

    float vals[PER];
    float sum = 0.f, sq = 0.f;
    #pragma unroll
    for (int i = 0; i < PER; ++i) {
        vals[i] = xr[lane + i * 64];
        sum += vals[i];
        sq += vals[i] * vals[i];
    }
    #pragma unroll
    for (int o = 32; o > 0; o >>= 1) {
        sum += __shfl_xor(sum, o, 64);
        sq  += __shfl_xor(sq, o, 64);
    }
    float mu = sum / (float)D;
    float var = sq / (float)D - mu * mu;
    float rstd = rsqrtf(var + LN_EPS);
    #pragma unroll
    for (int i = 0; i < PER; ++i) {
        int c = lane + i * 64;
        float y = (vals[i] - mu) * rstd * g[c] + beta[c];
        xr[c] = fmaxf(y, 0.f);
    }
}

// ---------------------------------------------------------------------------
extern "C" void kernel_launch(void* const* d_in, const int* in_sizes, int n_in,
                              void* d_out, int out_size, void* d_ws, size_t ws_size,
                              hipStream_t stream) {
    const float* v     = (const float*)d_in[0];
    const float* ew    = (const float*)d_in[1];
    const float* eps   = (const float*)d_in[2];
    const float* w1    = (const float*)d_in[3];
    const float* b1    = (const float*)d_in[4];
    const float* g1    = (const float*)d_in[5];
    const float* beta1 = (const float*)d_in[6];
    const float* w2    = (const float*)d_in[7];
    const float* b2    = (const float*)d_in[8];
    const float* g2    = (const float*)d_in[9];
    const float* beta2 = (const float*)d_in[10];
    const int*   src   = (const int*)d_in[11];
    const int*   dst   = (const int*)d_in[12];

    int N = in_sizes[0] / D_IN;     // 50000
    int E = in_sizes[1];            // 800000

    float* out = (float*)d_out;

    // workspace layout (256B-aligned chunks)
    char* ws = (char*)d_ws;
    size_t off = 0;
    ushort* vb   = (ushort*)(ws + off); off += (size_t)N * D_IN * 2;            // 25.6 MB
    ushort* aggb = (ushort*)(ws + off); off += (size_t)N * D_IN * 2;            // 25.6 MB
    ushort* h1b  = (ushort*)(ws + off); off += (size_t)N * D_HID * 2;           // 51.2 MB
    ushort* w1b  = (ushort*)(ws + off); off += (size_t)D_HID * D_IN * 2;        // 256 KB
    ushort* w2b  = (ushort*)(ws + off); off += (size_t)D_OUT * D_HID * 2;       // 256 KB
    int* offs     = (int*)(ws + off); off += (size_t)(N + 256) * 4;
    int* cursor   = (int*)(ws + off); off += (size_t)(N + 256) * 4;
    int* bsum     = (int*)(ws + off); off += 1024;
    int* perm_src = (int*)(ws + off); off += (size_t)E * 4;
    float* perm_w = (float*)(ws + off); off += (size_t)E * 4;

    int nb = (N + SCAN_B - 1) / SCAN_B;

    // 1) CSR by dst
    zero_kernel<<<(N + 255) / 256, 256, 0, stream>>>(cursor, N);
    hist_kernel<<<(E + 255) / 256, 256, 0, stream>>>(dst, cursor, E);
    scan1_kernel<<<nb, SCAN_B, 0, stream>>>(cursor, offs, bsum, N);
    scan2_kernel<<<1, 128, 0, stream>>>(bsum, nb);
    scan3_kernel<<<nb, SCAN_B, 0, stream>>>(offs, cursor, bsum, N, E);
    fill_kernel<<<(E + 255) / 256, 256, 0, stream>>>(src, dst, ew, cursor, perm_src, perm_w, E);

    // 2) v -> bf16, weights -> bf16
    cvt_bf16_kernel<<<((size_t)N * D_IN / 4 + 255) / 256, 256, 0, stream>>>(v, vb, N * D_IN / 4);
    cvt_bf16_kernel<<<(D_HID * D_IN / 4 + 255) / 256, 256, 0, stream>>>(w1, w1b, D_HID * D_IN / 4);
    cvt_bf16_kernel<<<(D_OUT * D_HID / 4 + 255) / 256, 256, 0, stream>>>(w2, w2b, D_OUT * D_HID / 4);

    // 3) aggregate (bf16 gather) -> bf16
    aggregate_kernel<<<(N + 3) / 4, 256, 0, stream>>>(vb, eps, offs, perm_src, perm_w, aggb, N);

    // 4) h1b = bf16(aggb @ w1b^T + b1)
    dim3 grid1(D_HID / 128, (N + 127) / 128);
    gemm_mfma_kernel<1><<<grid1, 256, 0, stream>>>(aggb, w1b, b1, h1b, N, D_HID, D_IN);

    // 5) h1b = relu(LN(h1b)) in-place
    ln_relu_bf16_kernel<<<(N + 3) / 4, 256, 0, stream>>>(h1b, g1, beta1, N);

    // 6) out = h1b @ w2b^T + b2  (fp32)
    dim3 grid2(D_OUT / 128, (N + 127) / 128);
    gemm_mfma_kernel<0><<<grid2, 256, 0, stream>>>(h1b, w2b, b2, out, N, D_OUT, D_HID);

    // 7) out = relu(LN(out)) in-place
    ln_relu_kernel<D_OUT><<<(N + 3) / 4, 256, 0, stream>>>(out, g2, beta2, N);
}

// Round 6
// 363.727 us; speedup vs baseline: 9.3595x; 1.0655x over previous
//
#include <hip/hip_runtime.h>

#define D_IN 256
#define D_HID 512
#define D_OUT 256
#define LN_EPS 1e-5f
#define SCAN_B 512

typedef __attribute__((ext_vector_type(8))) short bf16x8;
typedef __attribute__((ext_vector_type(4))) float f32x4;

__device__ __forceinline__ ushort f2bf(float x) {
    union { float f; unsigned u; } c; c.f = x;
    unsigned r = c.u + 0x7FFFu + ((c.u >> 16) & 1u);   // round-to-nearest-even
    return (ushort)(r >> 16);
}
__device__ __forceinline__ float bf2f(unsigned b) {
    union { unsigned u; float f; } c; c.u = b << 16;
    return c.f;
}

// ---------------------------------------------------------------------------
// CSR build (counting sort by dst)
// ---------------------------------------------------------------------------
__global__ void zero_kernel(int* __restrict__ p, int n) {
    int i = blockIdx.x * 256 + threadIdx.x;
    if (i < n) p[i] = 0;
}

__global__ void hist_kernel(const int* __restrict__ dst, int* __restrict__ cnt, int E) {
    int e = blockIdx.x * 256 + threadIdx.x;
    if (e < E) atomicAdd(&cnt[dst[e]], 1);
}

__global__ __launch_bounds__(SCAN_B) void scan1_kernel(const int* __restrict__ cnt,
                                                       int* __restrict__ offs,
                                                       int* __restrict__ bsum, int n) {
    __shared__ int s[SCAN_B];
    int i = blockIdx.x * SCAN_B + threadIdx.x;
    int x = (i < n) ? cnt[i] : 0;
    s[threadIdx.x] = x;
    __syncthreads();
    for (int o = 1; o < SCAN_B; o <<= 1) {
        int t = (threadIdx.x >= (unsigned)o) ? s[threadIdx.x - o] : 0;
        __syncthreads();
        s[threadIdx.x] += t;
        __syncthreads();
    }
    if (i < n) offs[i] = s[threadIdx.x] - x;
    if (threadIdx.x == SCAN_B - 1) bsum[blockIdx.x] = s[threadIdx.x];
}

__global__ __launch_bounds__(128) void scan2_kernel(int* __restrict__ bsum, int nb) {
    __shared__ int s[128];
    int x = (threadIdx.x < (unsigned)nb) ? bsum[threadIdx.x] : 0;
    s[threadIdx.x] = x;
    __syncthreads();
    for (int o = 1; o < 128; o <<= 1) {
        int t = (threadIdx.x >= (unsigned)o) ? s[threadIdx.x - o] : 0;
        __syncthreads();
        s[threadIdx.x] += t;
        __syncthreads();
    }
    if (threadIdx.x < (unsigned)nb) bsum[threadIdx.x] = s[threadIdx.x] - x;
}

__global__ __launch_bounds__(SCAN_B) void scan3_kernel(int* __restrict__ offs,
                                                       int* __restrict__ cursor,
                                                       const int* __restrict__ bsum,
                                                       int n, int E) {
    int i = blockIdx.x * SCAN_B + threadIdx.x;
    if (i < n) {
        int v0 = offs[i] + bsum[blockIdx.x];
        offs[i] = v0;
        cursor[i] = v0;
    }
    if (i == 0) offs[n] = E;
}

// counting-sort fill: one 8B scatter per edge (src, weight-bits)
__global__ void fill_kernel(const int* __restrict__ src, const int* __restrict__ dst,
                            const float* __restrict__ ew, int* __restrict__ cursor,
                            int2* __restrict__ perm, int E) {
    int e = blockIdx.x * 256 + threadIdx.x;
    if (e >= E) return;
    int p = atomicAdd(&cursor[dst[e]], 1);
    perm[p] = make_int2(src[e], __float_as_int(ew[e]));
}

// ---------------------------------------------------------------------------
// fp32 -> bf16 conversion (v)
// ---------------------------------------------------------------------------
__global__ void cvt_bf16_kernel(const float* __restrict__ in, ushort* __restrict__ out, int n4) {
    int i = blockIdx.x * 256 + threadIdx.x;
    if (i >= n4) return;
    float4 x = ((const float4*)in)[i];
    ((ushort4*)out)[i] = make_ushort4(f2bf(x.x), f2bf(x.y), f2bf(x.z), f2bf(x.w));
}

// both weight matrices in one launch (each 131072 floats = 32768 float4)
__global__ void cvt_w_kernel(const float* __restrict__ w1, const float* __restrict__ w2,
                             ushort* __restrict__ w1b, ushort* __restrict__ w2b) {
    int i = blockIdx.x * 256 + threadIdx.x;     // 0..65535
    const float* src; ushort* dst; int j;
    if (i < 32768) { src = w1; dst = w1b; j = i; }
    else           { src = w2; dst = w2b; j = i - 32768; }
    float4 x = ((const float4*)src)[j];
    ((ushort4*)dst)[j] = make_ushort4(f2bf(x.x), f2bf(x.y), f2bf(x.z), f2bf(x.w));
}

// ---------------------------------------------------------------------------
// agg_bf16[n] = bf16( eps*vb[n] + sum_{e:dst=n} w_e * vb[src_e] )
// one wave/node, bf16 gather, int2 edge records, unroll x4
// ---------------------------------------------------------------------------
__global__ __launch_bounds__(256) void aggregate_kernel(
    const ushort* __restrict__ vb, const float* __restrict__ eps_p,
    const int* __restrict__ offs, const int2* __restrict__ perm,
    ushort* __restrict__ aggb, int N) {
    int node = blockIdx.x * 4 + (threadIdx.x >> 6);
    if (node >= N) return;
    int lane = threadIdx.x & 63;
    int beg = offs[node], end = offs[node + 1];
    float a0 = 0.f, a1 = 0.f, a2 = 0.f, a3 = 0.f;

    int i = beg;
    for (; i + 4 <= end; i += 4) {
        int2 p0 = perm[i + 0], p1 = perm[i + 1], p2 = perm[i + 2], p3 = perm[i + 3];
        float w0 = __int_as_float(p0.y), w1 = __int_as_float(p1.y);
        float w2 = __int_as_float(p2.y), w3 = __int_as_float(p3.y);
        ushort4 r0 = ((const ushort4*)(vb + (size_t)p0.x * D_IN))[lane];
        ushort4 r1 = ((const ushort4*)(vb + (size_t)p1.x * D_IN))[lane];
        ushort4 r2 = ((const ushort4*)(vb + (size_t)p2.x * D_IN))[lane];
        ushort4 r3 = ((const ushort4*)(vb + (size_t)p3.x * D_IN))[lane];
        a0 += w0 * bf2f(r0.x) + w1 * bf2f(r1.x) + w2 * bf2f(r2.x) + w3 * bf2f(r3.x);
        a1 += w0 * bf2f(r0.y) + w1 * bf2f(r1.y) + w2 * bf2f(r2.y) + w3 * bf2f(r3.y);
        a2 += w0 * bf2f(r0.z) + w1 * bf2f(r1.z) + w2 * bf2f(r2.z) + w3 * bf2f(r3.z);
        a3 += w0 * bf2f(r0.w) + w1 * bf2f(r1.w) + w2 * bf2f(r2.w) + w3 * bf2f(r3.w);
    }
    for (; i < end; ++i) {
        int2 p = perm[i];
        float w = __int_as_float(p.y);
        ushort4 r = ((const ushort4*)(vb + (size_t)p.x * D_IN))[lane];
        a0 += w * bf2f(r.x); a1 += w * bf2f(r.y);
        a2 += w * bf2f(r.z); a3 += w * bf2f(r.w);
    }
    float eps = eps_p[0];
    ushort4 m = ((const ushort4*)(vb + (size_t)node * D_IN))[lane];
    a0 += eps * bf2f(m.x); a1 += eps * bf2f(m.y);
    a2 += eps * bf2f(m.z); a3 += eps * bf2f(m.w);
    ((ushort4*)(aggb + (size_t)node * D_IN))[lane] =
        make_ushort4(f2bf(a0), f2bf(a1), f2bf(a2), f2bf(a3));
}

// ---------------------------------------------------------------------------
// Fused GEMM + bias + LayerNorm + ReLU.
//   out[m][:] = relu(LN(A[m][:] @ B^T + bias) * g + beta)
// Block = 32 rows x COLS (full output width), 4 waves; wave w owns cols
// [w*CW, (w+1)*CW). 16x16x32 bf16 MFMA, BK=32, global_load_lds staging.
// COLS in {256,512}; K mult of 32; M guarded.
// ---------------------------------------------------------------------------
template <int COLS, int WRITE_BF16>
__global__ __launch_bounds__(256) void gemm_ln_kernel(
    const ushort* __restrict__ A, const ushort* __restrict__ B,
    const float* __restrict__ bias, const float* __restrict__ g,
    const float* __restrict__ beta, void* __restrict__ Cv, int M, int K) {
    constexpr int CW = COLS / 4;      // cols per wave
    constexpr int CF = CW / 16;       // col fragments per wave
    __shared__ ushort As[32 * 32];
    __shared__ ushort Bs[COLS * 32];
    __shared__ float red[2][32][4];   // [sum|sq][row][wave]
    __shared__ float mu_s[32], rs_s[32];

    int t = threadIdx.x;
    int w = t >> 6, lane = t & 63;
    int row0 = blockIdx.x * 32;
    int fr = lane & 15, q = lane >> 4, kb = q * 8;
    int lrow = lane >> 2;             // 0..15: row within 16-row staging chunk
    int lcol = (lane & 3) * 8;        // k-offset (8 bf16 = 16B)

    f32x4 acc[2][CF];
    #pragma unroll
    for (int i = 0; i < 2; ++i)
        #pragma unroll
        for (int c = 0; c < CF; ++c) {
            f32x4 z = {0.f, 0.f, 0.f, 0.f};
            acc[i][c] = z;
        }

    for (int k0 = 0; k0 < K; k0 += 32) {
        // stage B: wave w stages rows [w*CW, (w+1)*CW) in 16-row chunks
        #pragma unroll
        for (int c = 0; c < CF; ++c) {
            int br = w * CW + c * 16 + lrow;
            const ushort* gp = B + (size_t)br * K + k0 + lcol;
            __builtin_amdgcn_global_load_lds(
                (const __attribute__((address_space(1))) void*)gp,
                (__attribute__((address_space(3))) void*)(&Bs[(w * CW + c * 16) * 32]),
                16, 0, 0);
        }
        // stage A: waves 0,1 stage 16 rows each
        if (w < 2) {
            int ar = row0 + w * 16 + lrow;
            if (ar > M - 1) ar = M - 1;
            const ushort* gp = A + (size_t)ar * K + k0 + lcol;
            __builtin_amdgcn_global_load_lds(
                (const __attribute__((address_space(1))) void*)gp,
                (__attribute__((address_space(3))) void*)(&As[(w * 16) * 32]),
                16, 0, 0);
        }
        __syncthreads();

        bf16x8 af[2], bf[CF];
        af[0] = *(const bf16x8*)&As[fr * 32 + kb];
        af[1] = *(const bf16x8*)&As[(16 + fr) * 32 + kb];
        #pragma unroll
        for (int c = 0; c < CF; ++c)
            bf[c] = *(const bf16x8*)&Bs[(w * CW + c * 16 + fr) * 32 + kb];
        #pragma unroll
        for (int i = 0; i < 2; ++i)
            #pragma unroll
            for (int c = 0; c < CF; ++c)
                acc[i][c] = __builtin_amdgcn_mfma_f32_16x16x32_bf16(af[i], bf[c], acc[i][c], 0, 0, 0);
        __syncthreads();
    }

    // epilogue: bias, then per-row LN stats
    float bi[CF], gg[CF], bb[CF];
    #pragma unroll
    for (int c = 0; c < CF; ++c) {
        int col = w * CW + c * 16 + fr;
        bi[c] = bias[col]; gg[c] = g[col]; bb[c] = beta[col];
    }

    // per-(i,r): sum over this wave's CW cols via 16-lane butterfly over fr
    #pragma unroll
    for (int i = 0; i < 2; ++i) {
        #pragma unroll
        for (int r = 0; r < 4; ++r) {
            float s = 0.f, sq = 0.f;
            #pragma unroll
            for (int c = 0; c < CF; ++c) {
                float x = acc[i][c][r] + bi[c];
                acc[i][c][r] = x;
                s += x; sq += x * x;
            }
            #pragma unroll
            for (int o = 1; o < 16; o <<= 1) {
                s  += __shfl_xor(s, o, 64);
                sq += __shfl_xor(sq, o, 64);
            }
            if (fr == 0) {
                int row = i * 16 + q * 4 + r;
                red[0][row][w] = s;
                red[1][row][w] = sq;
            }
        }
    }
    __syncthreads();
    if (t < 32) {
        float s  = red[0][t][0] + red[0][t][1] + red[0][t][2] + red[0][t][3];
        float sq = red[1][t][0] + red[1][t][1] + red[1][t][2] + red[1][t][3];
        float mu = s / (float)COLS;
        float var = sq / (float)COLS - mu * mu;
        mu_s[t] = mu;
        rs_s[t] = rsqrtf(var + LN_EPS);
    }
    __syncthreads();

    #pragma unroll
    for (int i = 0; i < 2; ++i) {
        #pragma unroll
        for (int r = 0; r < 4; ++r) {
            int row = i * 16 + q * 4 + r;
            int grow = row0 + row;
            if (grow >= M) continue;
            float mu = mu_s[row], rs = rs_s[row];
            #pragma unroll
            for (int c = 0; c < CF; ++c) {
                int col = w * CW + c * 16 + fr;
                float y = (acc[i][c][r] - mu) * rs * gg[c] + bb[c];
                y = fmaxf(y, 0.f);
                if (WRITE_BF16)
                    ((ushort*)Cv)[(size_t)grow * COLS + col] = f2bf(y);
                else
                    ((float*)Cv)[(size_t)grow * COLS + col] = y;
            }
        }
    }
}

// ---------------------------------------------------------------------------
extern "C" void kernel_launch(void* const* d_in, const int* in_sizes, int n_in,
                              void* d_out, int out_size, void* d_ws, size_t ws_size,
                              hipStream_t stream) {
    const float* v     = (const float*)d_in[0];
    const float* ew    = (const float*)d_in[1];
    const float* eps   = (const float*)d_in[2];
    const float* w1    = (const float*)d_in[3];
    const float* b1    = (const float*)d_in[4];
    const float* g1    = (const float*)d_in[5];
    const float* beta1 = (const float*)d_in[6];
    const float* w2    = (const float*)d_in[7];
    const float* b2    = (const float*)d_in[8];
    const float* g2    = (const float*)d_in[9];
    const float* beta2 = (const float*)d_in[10];
    const int*   src   = (const int*)d_in[11];
    const int*   dst   = (const int*)d_in[12];

    int N = in_sizes[0] / D_IN;     // 50000
    int E = in_sizes[1];            // 800000

    float* out = (float*)d_out;

    // workspace layout (256B-aligned chunks)
    char* ws = (char*)d_ws;
    size_t off = 0;
    ushort* vb   = (ushort*)(ws + off); off += (size_t)N * D_IN * 2;            // 25.6 MB
    ushort* aggb = (ushort*)(ws + off); off += (size_t)N * D_IN * 2;            // 25.6 MB
    ushort* h1b  = (ushort*)(ws + off); off += (size_t)N * D_HID * 2;           // 51.2 MB
    ushort* w1b  = (ushort*)(ws + off); off += (size_t)D_HID * D_IN * 2;        // 256 KB
    ushort* w2b  = (ushort*)(ws + off); off += (size_t)D_OUT * D_HID * 2;       // 256 KB
    int* offs     = (int*)(ws + off); off += (size_t)(N + 256) * 4;
    int* cursor   = (int*)(ws + off); off += (size_t)(N + 256) * 4;
    int* bsum     = (int*)(ws + off); off += 1024;
    int2* perm    = (int2*)(ws + off); off += (size_t)E * 8;

    int nb = (N + SCAN_B - 1) / SCAN_B;

    // 1) CSR by dst
    zero_kernel<<<(N + 255) / 256, 256, 0, stream>>>(cursor, N);
    hist_kernel<<<(E + 255) / 256, 256, 0, stream>>>(dst, cursor, E);
    scan1_kernel<<<nb, SCAN_B, 0, stream>>>(cursor, offs, bsum, N);
    scan2_kernel<<<1, 128, 0, stream>>>(bsum, nb);
    scan3_kernel<<<nb, SCAN_B, 0, stream>>>(offs, cursor, bsum, N, E);
    fill_kernel<<<(E + 255) / 256, 256, 0, stream>>>(src, dst, ew, cursor, perm, E);

    // 2) casts
    cvt_bf16_kernel<<<((size_t)N * D_IN / 4 + 255) / 256, 256, 0, stream>>>(v, vb, N * D_IN / 4);
    cvt_w_kernel<<<256, 256, 0, stream>>>(w1, w2, w1b, w2b);

    // 3) aggregate (bf16 gather) -> bf16
    aggregate_kernel<<<(N + 3) / 4, 256, 0, stream>>>(vb, eps, offs, perm, aggb, N);

    // 4) h1b = relu(LN(aggb @ w1b^T + b1))    [fused]
    int mblocks = (N + 31) / 32;
    gemm_ln_kernel<D_HID, 1><<<mblocks, 256, 0, stream>>>(
        aggb, w1b, b1, g1, beta1, h1b, N, D_IN);

    // 5) out = relu(LN(h1b @ w2b^T + b2))     [fused, fp32 out]
    gemm_ln_kernel<D_OUT, 0><<<mblocks, 256, 0, stream>>>(
        h1b, w2b, b2, g2, beta2, out, N, D_HID);
}